// Round 4
// baseline (992.983 us; speedup 1.0000x reference)
//
#include <hip/hip_runtime.h>
#include <math.h>

#define D_IN 128
#define D_OUT 64
#define BM 64
#define BNT 256
#define KB 32
#define SCALE_PARAM 2.0f

typedef unsigned short ushortt;

__device__ __forceinline__ ushortt f2bf(float f) {
    union { float f; unsigned u; } cv; cv.f = f;
    unsigned u = cv.u;
    return (ushortt)((u + 0x7FFFu + ((u >> 16) & 1u)) >> 16);
}
__device__ __forceinline__ float bflo(unsigned w) {
    union { unsigned u; float f; } cv; cv.u = w << 16;
    return cv.f;
}
__device__ __forceinline__ float bfhi(unsigned w) {
    union { unsigned u; float f; } cv; cv.u = w & 0xFFFF0000u;
    return cv.f;
}

// ---------------- fused qkv+skip GEMM ----------------
__global__ __launch_bounds__(256) void fused_gemm_kernel(
    const float* __restrict__ x,
    const float* __restrict__ Wq, const float* __restrict__ bq,
    const float* __restrict__ Wk, const float* __restrict__ bk,
    const float* __restrict__ Wv, const float* __restrict__ bv,
    const float* __restrict__ Ws, const float* __restrict__ bs,
    ushortt* __restrict__ q, ushortt* __restrict__ kk, ushortt* __restrict__ v,
    float* __restrict__ skip, int N)
{
    __shared__ float xs[KB][BM + 4];
    __shared__ float wsh[KB][BNT];

    const int t = threadIdx.x;
    const int row0 = blockIdx.x * BM;
    const int tx = t & 31;
    const int ty = t >> 5;

    float acc[8][8];
#pragma unroll
    for (int i = 0; i < 8; ++i)
#pragma unroll
        for (int j = 0; j < 8; ++j) acc[i][j] = 0.f;

    const int m = t >> 6;
    const int c = t & 63;
    const float* Wm = (m == 0) ? Wq : (m == 1) ? Wk : (m == 2) ? Wv : Ws;

    for (int k0 = 0; k0 < D_IN; k0 += KB) {
#pragma unroll
        for (int r = 0; r < KB; ++r)
            wsh[r][t] = Wm[(k0 + r) * D_OUT + c];
        {
            int r = t >> 2;
            int c4b = t & 3;
#pragma unroll
            for (int it = 0; it < 2; ++it) {
                int cc = c4b + it * 4;
                int grow = row0 + r;
                float4 xv = make_float4(0.f, 0.f, 0.f, 0.f);
                if (grow < N)
                    xv = *reinterpret_cast<const float4*>(&x[(size_t)grow * D_IN + k0 + cc * 4]);
                xs[cc * 4 + 0][r] = xv.x;
                xs[cc * 4 + 1][r] = xv.y;
                xs[cc * 4 + 2][r] = xv.z;
                xs[cc * 4 + 3][r] = xv.w;
            }
        }
        __syncthreads();
#pragma unroll
        for (int kq = 0; kq < KB; ++kq) {
            float a[8], b[8];
            float4 a0 = *reinterpret_cast<const float4*>(&xs[kq][ty * 8]);
            float4 a1 = *reinterpret_cast<const float4*>(&xs[kq][ty * 8 + 4]);
            float4 b0 = *reinterpret_cast<const float4*>(&wsh[kq][tx * 8]);
            float4 b1 = *reinterpret_cast<const float4*>(&wsh[kq][tx * 8 + 4]);
            a[0] = a0.x; a[1] = a0.y; a[2] = a0.z; a[3] = a0.w;
            a[4] = a1.x; a[5] = a1.y; a[6] = a1.z; a[7] = a1.w;
            b[0] = b0.x; b[1] = b0.y; b[2] = b0.z; b[3] = b0.w;
            b[4] = b1.x; b[5] = b1.y; b[6] = b1.z; b[7] = b1.w;
#pragma unroll
            for (int i = 0; i < 8; ++i)
#pragma unroll
                for (int j = 0; j < 8; ++j)
                    acc[i][j] = fmaf(a[i], b[j], acc[i][j]);
        }
        __syncthreads();
    }

    const int mo = (tx * 8) >> 6;
    const int co = (tx * 8) & 63;
    const float* bp = (mo == 0) ? bq : (mo == 1) ? bk : (mo == 2) ? bv : bs;
#pragma unroll
    for (int i = 0; i < 8; ++i) {
        int grow = row0 + ty * 8 + i;
        if (grow >= N) continue;
        float o[8];
#pragma unroll
        for (int j = 0; j < 8; ++j) o[j] = acc[i][j] + bp[co + j];
        if (mo == 3) {
            *reinterpret_cast<float4*>(&skip[(size_t)grow * D_OUT + co])     = make_float4(o[0], o[1], o[2], o[3]);
            *reinterpret_cast<float4*>(&skip[(size_t)grow * D_OUT + co + 4]) = make_float4(o[4], o[5], o[6], o[7]);
        } else {
            ushortt* op = (mo == 0) ? q : (mo == 1) ? kk : v;
            uint4 pk;
            pk.x = (unsigned)f2bf(o[0]) | ((unsigned)f2bf(o[1]) << 16);
            pk.y = (unsigned)f2bf(o[2]) | ((unsigned)f2bf(o[3]) << 16);
            pk.z = (unsigned)f2bf(o[4]) | ((unsigned)f2bf(o[5]) << 16);
            pk.w = (unsigned)f2bf(o[6]) | ((unsigned)f2bf(o[7]) << 16);
            *reinterpret_cast<uint4*>(&op[(size_t)grow * D_OUT + co]) = pk;
        }
    }
}

// ---------------- dst histogram ----------------
__global__ __launch_bounds__(256) void hist_kernel(
    const int* __restrict__ dst, int* __restrict__ cnt, int E)
{
    int base = (blockIdx.x * 256 + threadIdx.x) * 4;
    if (base + 3 < E) {
        int4 d = *reinterpret_cast<const int4*>(&dst[base]);
        atomicAdd(&cnt[d.x], 1); atomicAdd(&cnt[d.y], 1);
        atomicAdd(&cnt[d.z], 1); atomicAdd(&cnt[d.w], 1);
    } else {
        for (int i = base; i < E; ++i) atomicAdd(&cnt[dst[i]], 1);
    }
}

// ---------------- scan phases ----------------
__global__ __launch_bounds__(256) void scan1_kernel(
    const int* __restrict__ cnt, int* __restrict__ row_start,
    int* __restrict__ bsum, int N)
{
    const int t = threadIdx.x;
    const int base = blockIdx.x * 1024 + t * 4;
    int v0 = 0, v1 = 0, v2 = 0, v3 = 0;
    if (base + 3 < N) {
        int4 c = *reinterpret_cast<const int4*>(&cnt[base]);
        v0 = c.x; v1 = c.y; v2 = c.z; v3 = c.w;
    } else {
        if (base < N)     v0 = cnt[base];
        if (base + 1 < N) v1 = cnt[base + 1];
        if (base + 2 < N) v2 = cnt[base + 2];
    }
    const int tsum = v0 + v1 + v2 + v3;
    int x = tsum;
    const int lane = t & 63;
#pragma unroll
    for (int off = 1; off < 64; off <<= 1) {
        int n = __shfl_up(x, off, 64);
        if (lane >= off) x += n;
    }
    __shared__ int wsum[4];
    const int wid = t >> 6;
    if (lane == 63) wsum[wid] = x;
    __syncthreads();
    int wofs = 0;
    for (int w = 0; w < wid; ++w) wofs += wsum[w];
    const int incl = x + wofs;
    const int excl = incl - tsum;
    if (base < N)     row_start[base]     = excl;
    if (base + 1 < N) row_start[base + 1] = excl + v0;
    if (base + 2 < N) row_start[base + 2] = excl + v0 + v1;
    if (base + 3 < N) row_start[base + 3] = excl + v0 + v1 + v2;
    if (t == 255) bsum[blockIdx.x] = incl;
}

__global__ void scan2_kernel(int* bsum, int NB, int* row_start_N) {
    if (threadIdx.x == 0) {
        int run = 0;
        for (int i = 0; i < NB; ++i) {
            int tv = bsum[i];
            bsum[i] = run;
            run += tv;
        }
        *row_start_N = run;
    }
}

__global__ __launch_bounds__(256) void scan3_kernel(
    int* __restrict__ row_start, int* __restrict__ ofs,
    const int* __restrict__ bsum, int N)
{
    const int base = blockIdx.x * 1024 + threadIdx.x * 4;
    const int add = bsum[blockIdx.x];
#pragma unroll
    for (int i = 0; i < 4; ++i) {
        if (base + i < N) {
            int vv = row_start[base + i] + add;
            row_start[base + i] = vv;
            ofs[base + i] = vv;
        }
    }
}

// ---------------- bucket scatter (src only) ----------------
__global__ __launch_bounds__(256) void scatter_sort_kernel(
    const int* __restrict__ src, const int* __restrict__ dst,
    int* __restrict__ ofs, int* __restrict__ sorted_src, int E)
{
    const int e = blockIdx.x * 256 + threadIdx.x;
    if (e >= E) return;
    int d = dst[e];
    int pos = atomicAdd(&ofs[d], 1);
    sorted_src[pos] = src[e];
}

// ---------------- per-node logits + stats ----------------
// wave per node; 8-lane group per edge; q row register-resident
__global__ __launch_bounds__(256) void node_logit_kernel(
    const ushortt* __restrict__ q, const ushortt* __restrict__ k,
    const int* __restrict__ sorted_src, const int* __restrict__ row_start,
    float* __restrict__ alpha_sorted, float* __restrict__ stats, int N)
{
    const int t = threadIdx.x;
    const int wid = t >> 6, lane = t & 63;
    const int g = lane >> 3;       // edge slot 0..7
    const int c8 = lane & 7;       // channel octet
    const int node = blockIdx.x * 4 + wid;
    float lsum = 0.f, lsq = 0.f;
    if (node < N) {
        uint4 qw = reinterpret_cast<const uint4*>(q + (size_t)node * D_OUT)[c8];
        const float q0 = bflo(qw.x), q1 = bfhi(qw.x), q2 = bflo(qw.y), q3 = bfhi(qw.y);
        const float q4 = bflo(qw.z), q5 = bfhi(qw.z), q6 = bflo(qw.w), q7 = bfhi(qw.w);
        const int s0 = row_start[node], s1 = row_start[node + 1];
        for (int j = s0; j < s1; j += 8) {
            const int jj = j + g;
            const bool valid = jj < s1;
            float p = 0.f;
            if (valid) {
                int s = sorted_src[jj];
                uint4 kw = reinterpret_cast<const uint4*>(k + (size_t)s * D_OUT)[c8];
                p = q0 * bflo(kw.x);
                p = fmaf(q1, bfhi(kw.x), p);
                p = fmaf(q2, bflo(kw.y), p);
                p = fmaf(q3, bfhi(kw.y), p);
                p = fmaf(q4, bflo(kw.z), p);
                p = fmaf(q5, bfhi(kw.z), p);
                p = fmaf(q6, bflo(kw.w), p);
                p = fmaf(q7, bfhi(kw.w), p);
            }
            p += __shfl_xor(p, 1, 8);
            p += __shfl_xor(p, 2, 8);
            p += __shfl_xor(p, 4, 8);
            if (valid && c8 == 0) {
                float a = p * 0.125f;   // 1/sqrt(64)
                alpha_sorted[jj] = a;
                lsum += a;
                lsq += a * a;
            }
        }
    }
#pragma unroll
    for (int off = 1; off < 64; off <<= 1) {
        lsum += __shfl_xor(lsum, off, 64);
        lsq  += __shfl_xor(lsq,  off, 64);
    }
    __shared__ float red[2][4];
    if (lane == 0) { red[0][wid] = lsum; red[1][wid] = lsq; }
    __syncthreads();
    if (t == 0) {
        atomicAdd(&stats[0], red[0][0] + red[0][1] + red[0][2] + red[0][3]);
        atomicAdd(&stats[1], red[1][0] + red[1][1] + red[1][2] + red[1][3]);
    }
}

// ---------------- finalize mean/std ----------------
__global__ void finalize_stats_kernel(float* stats, int E) {
    if (threadIdx.x == 0) {
        float s = stats[0], s2 = stats[1];
        float mean = s / (float)E;
        float var = (s2 - (float)E * mean * mean) / (float)(E - 1);
        stats[2] = mean;
        stats[3] = SCALE_PARAM / sqrtf(var);
    }
}

// ---------------- per-node accumulate: sigmoid + v gather ----------------
__global__ __launch_bounds__(256) void node_gather_kernel(
    const ushortt* __restrict__ v, const int* __restrict__ sorted_src,
    const float* __restrict__ alpha_sorted, const int* __restrict__ row_start,
    const float* __restrict__ stats, float* __restrict__ out, int N)
{
    const int t = threadIdx.x;
    const int wid = t >> 6, lane = t & 63;
    const int g = lane >> 3, c8 = lane & 7;
    const int node = blockIdx.x * 4 + wid;
    if (node >= N) return;
    const float mean = stats[2], coef = stats[3];
    float a0 = 0, a1 = 0, a2 = 0, a3 = 0, a4 = 0, a5 = 0, a6 = 0, a7 = 0;
    const int s0 = row_start[node], s1 = row_start[node + 1];
    for (int j = s0; j < s1; j += 8) {
        const int jj = j + g;
        if (jj < s1) {
            int s = sorted_src[jj];
            float al = alpha_sorted[jj];
            al = (al - mean) * coef;
            al = 1.f / (1.f + __expf(-al));
            uint4 vw = reinterpret_cast<const uint4*>(v + (size_t)s * D_OUT)[c8];
            a0 = fmaf(bflo(vw.x), al, a0); a1 = fmaf(bfhi(vw.x), al, a1);
            a2 = fmaf(bflo(vw.y), al, a2); a3 = fmaf(bfhi(vw.y), al, a3);
            a4 = fmaf(bflo(vw.z), al, a4); a5 = fmaf(bfhi(vw.z), al, a5);
            a6 = fmaf(bflo(vw.w), al, a6); a7 = fmaf(bfhi(vw.w), al, a7);
        }
    }
    // reduce across the 8 edge-groups (channels stay put)
#pragma unroll
    for (int off = 8; off < 64; off <<= 1) {
        a0 += __shfl_xor(a0, off, 64); a1 += __shfl_xor(a1, off, 64);
        a2 += __shfl_xor(a2, off, 64); a3 += __shfl_xor(a3, off, 64);
        a4 += __shfl_xor(a4, off, 64); a5 += __shfl_xor(a5, off, 64);
        a6 += __shfl_xor(a6, off, 64); a7 += __shfl_xor(a7, off, 64);
    }
    if (g == 0) {
        float* op = out + (size_t)node * D_OUT + c8 * 8;
        float4 c0 = *reinterpret_cast<float4*>(op);
        float4 c1 = *reinterpret_cast<float4*>(op + 4);
        c0.x += a0; c0.y += a1; c0.z += a2; c0.w += a3;
        c1.x += a4; c1.y += a5; c1.z += a6; c1.w += a7;
        *reinterpret_cast<float4*>(op)     = c0;
        *reinterpret_cast<float4*>(op + 4) = c1;
    }
}

extern "C" void kernel_launch(void* const* d_in, const int* in_sizes, int n_in,
                              void* d_out, int out_size, void* d_ws, size_t ws_size,
                              hipStream_t stream) {
    const float* x     = (const float*)d_in[0];
    const int*   eidx  = (const int*)d_in[1];
    const float* Wq    = (const float*)d_in[2];
    const float* bq    = (const float*)d_in[3];
    const float* Wk    = (const float*)d_in[4];
    const float* bk    = (const float*)d_in[5];
    const float* Wv    = (const float*)d_in[6];
    const float* bv    = (const float*)d_in[7];
    const float* Ws    = (const float*)d_in[8];
    const float* bs    = (const float*)d_in[9];
    float* out = (float*)d_out;

    const int N = in_sizes[0] / D_IN;
    const int E = in_sizes[1] / 2;
    const int* src = eidx;
    const int* dst = eidx + E;

    char* base = (char*)d_ws;
    size_t cur = 0;
    auto carve = [&](size_t bytes) -> char* {
        char* p = base + cur;
        cur = (cur + bytes + 255) & ~(size_t)255;
        return p;
    };
    const size_t nodebf = (size_t)N * D_OUT * sizeof(ushortt);
    ushortt* q          = (ushortt*)carve(nodebf);
    ushortt* k          = (ushortt*)carve(nodebf);
    ushortt* v          = (ushortt*)carve(nodebf);
    float* alpha_sorted = (float*)carve((size_t)E * sizeof(float));
    int*   sorted_src   = (int*)carve((size_t)E * sizeof(int));
    char*  zreg         = carve((size_t)N * sizeof(int) + 256);
    int*   cnt          = (int*)zreg;
    float* stats        = (float*)(zreg + (((size_t)N * sizeof(int) + 255) & ~(size_t)255));
    int*   row_start    = (int*)carve((size_t)(N + 1) * sizeof(int));
    int*   ofs          = (int*)carve((size_t)N * sizeof(int));
    const int NB = (N + 1023) / 1024;
    int*   bsum         = (int*)carve((size_t)NB * sizeof(int));

    hipMemsetAsync(zreg, 0, (size_t)N * sizeof(int) + 256, stream);

    // edge-index-only pipeline (independent of GEMM)
    hist_kernel<<<(E / 4 + 255) / 256, 256, 0, stream>>>(dst, cnt, E);
    scan1_kernel<<<NB, 256, 0, stream>>>(cnt, row_start, bsum, N);
    scan2_kernel<<<1, 64, 0, stream>>>(bsum, NB, &row_start[N]);
    scan3_kernel<<<NB, 256, 0, stream>>>(row_start, ofs, bsum, N);
    scatter_sort_kernel<<<(E + 255) / 256, 256, 0, stream>>>(
        src, dst, ofs, sorted_src, E);

    const int gemm_grid = (N + BM - 1) / BM;
    fused_gemm_kernel<<<gemm_grid, 256, 0, stream>>>(
        x, Wq, bq, Wk, bk, Wv, bv, Ws, bs, q, k, v, out, N);

    node_logit_kernel<<<(N + 3) / 4, 256, 0, stream>>>(
        q, k, sorted_src, row_start, alpha_sorted, stats, N);
    finalize_stats_kernel<<<1, 64, 0, stream>>>(stats, E);
    node_gather_kernel<<<(N + 3) / 4, 256, 0, stream>>>(
        v, sorted_src, alpha_sorted, row_start, stats, out, N);
}

// Round 5
// 401.865 us; speedup vs baseline: 2.4709x; 2.4709x over previous
//
#include <hip/hip_runtime.h>
#include <math.h>

#define D_IN 128
#define D_OUT 64
#define BM 64
#define BNT 256
#define KB 32
#define SCALE_PARAM 2.0f
#define NSLOT 64          // spread slots for stats atomics (64B-line spaced)
#define SLOT_STRIDE 16    // floats

typedef unsigned short ushortt;

__device__ __forceinline__ ushortt f2bf(float f) {
    union { float f; unsigned u; } cv; cv.f = f;
    unsigned u = cv.u;
    return (ushortt)((u + 0x7FFFu + ((u >> 16) & 1u)) >> 16);
}
__device__ __forceinline__ float bflo(unsigned w) {
    union { unsigned u; float f; } cv; cv.u = w << 16;
    return cv.f;
}
__device__ __forceinline__ float bfhi(unsigned w) {
    union { unsigned u; float f; } cv; cv.u = w & 0xFFFF0000u;
    return cv.f;
}

// ---------------- fused qkv+skip GEMM ----------------
__global__ __launch_bounds__(256) void fused_gemm_kernel(
    const float* __restrict__ x,
    const float* __restrict__ Wq, const float* __restrict__ bq,
    const float* __restrict__ Wk, const float* __restrict__ bk,
    const float* __restrict__ Wv, const float* __restrict__ bv,
    const float* __restrict__ Ws, const float* __restrict__ bs,
    ushortt* __restrict__ q, ushortt* __restrict__ kk, ushortt* __restrict__ v,
    float* __restrict__ skip, int N)
{
    __shared__ float xs[KB][BM + 4];
    __shared__ float wsh[KB][BNT];

    const int t = threadIdx.x;
    const int row0 = blockIdx.x * BM;
    const int tx = t & 31;
    const int ty = t >> 5;

    float acc[8][8];
#pragma unroll
    for (int i = 0; i < 8; ++i)
#pragma unroll
        for (int j = 0; j < 8; ++j) acc[i][j] = 0.f;

    const int m = t >> 6;
    const int c = t & 63;
    const float* Wm = (m == 0) ? Wq : (m == 1) ? Wk : (m == 2) ? Wv : Ws;

    for (int k0 = 0; k0 < D_IN; k0 += KB) {
#pragma unroll
        for (int r = 0; r < KB; ++r)
            wsh[r][t] = Wm[(k0 + r) * D_OUT + c];
        {
            int r = t >> 2;
            int c4b = t & 3;
#pragma unroll
            for (int it = 0; it < 2; ++it) {
                int cc = c4b + it * 4;
                int grow = row0 + r;
                float4 xv = make_float4(0.f, 0.f, 0.f, 0.f);
                if (grow < N)
                    xv = *reinterpret_cast<const float4*>(&x[(size_t)grow * D_IN + k0 + cc * 4]);
                xs[cc * 4 + 0][r] = xv.x;
                xs[cc * 4 + 1][r] = xv.y;
                xs[cc * 4 + 2][r] = xv.z;
                xs[cc * 4 + 3][r] = xv.w;
            }
        }
        __syncthreads();
#pragma unroll
        for (int kq = 0; kq < KB; ++kq) {
            float a[8], b[8];
            float4 a0 = *reinterpret_cast<const float4*>(&xs[kq][ty * 8]);
            float4 a1 = *reinterpret_cast<const float4*>(&xs[kq][ty * 8 + 4]);
            float4 b0 = *reinterpret_cast<const float4*>(&wsh[kq][tx * 8]);
            float4 b1 = *reinterpret_cast<const float4*>(&wsh[kq][tx * 8 + 4]);
            a[0] = a0.x; a[1] = a0.y; a[2] = a0.z; a[3] = a0.w;
            a[4] = a1.x; a[5] = a1.y; a[6] = a1.z; a[7] = a1.w;
            b[0] = b0.x; b[1] = b0.y; b[2] = b0.z; b[3] = b0.w;
            b[4] = b1.x; b[5] = b1.y; b[6] = b1.z; b[7] = b1.w;
#pragma unroll
            for (int i = 0; i < 8; ++i)
#pragma unroll
                for (int j = 0; j < 8; ++j)
                    acc[i][j] = fmaf(a[i], b[j], acc[i][j]);
        }
        __syncthreads();
    }

    const int mo = (tx * 8) >> 6;
    const int co = (tx * 8) & 63;
    const float* bp = (mo == 0) ? bq : (mo == 1) ? bk : (mo == 2) ? bv : bs;
#pragma unroll
    for (int i = 0; i < 8; ++i) {
        int grow = row0 + ty * 8 + i;
        if (grow >= N) continue;
        float o[8];
#pragma unroll
        for (int j = 0; j < 8; ++j) o[j] = acc[i][j] + bp[co + j];
        if (mo == 3) {
            *reinterpret_cast<float4*>(&skip[(size_t)grow * D_OUT + co])     = make_float4(o[0], o[1], o[2], o[3]);
            *reinterpret_cast<float4*>(&skip[(size_t)grow * D_OUT + co + 4]) = make_float4(o[4], o[5], o[6], o[7]);
        } else {
            ushortt* op = (mo == 0) ? q : (mo == 1) ? kk : v;
            uint4 pk;
            pk.x = (unsigned)f2bf(o[0]) | ((unsigned)f2bf(o[1]) << 16);
            pk.y = (unsigned)f2bf(o[2]) | ((unsigned)f2bf(o[3]) << 16);
            pk.z = (unsigned)f2bf(o[4]) | ((unsigned)f2bf(o[5]) << 16);
            pk.w = (unsigned)f2bf(o[6]) | ((unsigned)f2bf(o[7]) << 16);
            *reinterpret_cast<uint4*>(&op[(size_t)grow * D_OUT + co]) = pk;
        }
    }
}

// ---------------- dst histogram ----------------
__global__ __launch_bounds__(256) void hist_kernel(
    const int* __restrict__ dst, int* __restrict__ cnt, int E)
{
    int base = (blockIdx.x * 256 + threadIdx.x) * 4;
    if (base + 3 < E) {
        int4 d = *reinterpret_cast<const int4*>(&dst[base]);
        atomicAdd(&cnt[d.x], 1); atomicAdd(&cnt[d.y], 1);
        atomicAdd(&cnt[d.z], 1); atomicAdd(&cnt[d.w], 1);
    } else {
        for (int i = base; i < E; ++i) atomicAdd(&cnt[dst[i]], 1);
    }
}

// ---------------- scan phases ----------------
__global__ __launch_bounds__(256) void scan1_kernel(
    const int* __restrict__ cnt, int* __restrict__ row_start,
    int* __restrict__ bsum, int N)
{
    const int t = threadIdx.x;
    const int base = blockIdx.x * 1024 + t * 4;
    int v0 = 0, v1 = 0, v2 = 0, v3 = 0;
    if (base + 3 < N) {
        int4 c = *reinterpret_cast<const int4*>(&cnt[base]);
        v0 = c.x; v1 = c.y; v2 = c.z; v3 = c.w;
    } else {
        if (base < N)     v0 = cnt[base];
        if (base + 1 < N) v1 = cnt[base + 1];
        if (base + 2 < N) v2 = cnt[base + 2];
    }
    const int tsum = v0 + v1 + v2 + v3;
    int x = tsum;
    const int lane = t & 63;
#pragma unroll
    for (int off = 1; off < 64; off <<= 1) {
        int n = __shfl_up(x, off, 64);
        if (lane >= off) x += n;
    }
    __shared__ int wsum[4];
    const int wid = t >> 6;
    if (lane == 63) wsum[wid] = x;
    __syncthreads();
    int wofs = 0;
    for (int w = 0; w < wid; ++w) wofs += wsum[w];
    const int incl = x + wofs;
    const int excl = incl - tsum;
    if (base < N)     row_start[base]     = excl;
    if (base + 1 < N) row_start[base + 1] = excl + v0;
    if (base + 2 < N) row_start[base + 2] = excl + v0 + v1;
    if (base + 3 < N) row_start[base + 3] = excl + v0 + v1 + v2;
    if (t == 255) bsum[blockIdx.x] = incl;
}

__global__ void scan2_kernel(int* bsum, int NB, int* row_start_N) {
    if (threadIdx.x == 0) {
        int run = 0;
        for (int i = 0; i < NB; ++i) {
            int tv = bsum[i];
            bsum[i] = run;
            run += tv;
        }
        *row_start_N = run;
    }
}

__global__ __launch_bounds__(256) void scan3_kernel(
    int* __restrict__ row_start, int* __restrict__ ofs,
    const int* __restrict__ bsum, int N)
{
    const int base = blockIdx.x * 1024 + threadIdx.x * 4;
    const int add = bsum[blockIdx.x];
#pragma unroll
    for (int i = 0; i < 4; ++i) {
        if (base + i < N) {
            int vv = row_start[base + i] + add;
            row_start[base + i] = vv;
            ofs[base + i] = vv;
        }
    }
}

// ---------------- bucket scatter (src only) ----------------
__global__ __launch_bounds__(256) void scatter_sort_kernel(
    const int* __restrict__ src, const int* __restrict__ dst,
    int* __restrict__ ofs, int* __restrict__ sorted_src, int E)
{
    const int e = blockIdx.x * 256 + threadIdx.x;
    if (e >= E) return;
    int d = dst[e];
    int pos = atomicAdd(&ofs[d], 1);
    sorted_src[pos] = src[e];
}

// ---------------- per-node logits + stats (spread-slot atomics) --------
__global__ __launch_bounds__(256) void node_logit_kernel(
    const ushortt* __restrict__ q, const ushortt* __restrict__ k,
    const int* __restrict__ sorted_src, const int* __restrict__ row_start,
    float* __restrict__ alpha_sorted, float* __restrict__ slots, int N)
{
    const int t = threadIdx.x;
    const int wid = t >> 6, lane = t & 63;
    const int g = lane >> 3;       // edge slot 0..7
    const int c8 = lane & 7;       // channel octet
    const int node = blockIdx.x * 4 + wid;
    float lsum = 0.f, lsq = 0.f;
    if (node < N) {
        uint4 qw = reinterpret_cast<const uint4*>(q + (size_t)node * D_OUT)[c8];
        const float q0 = bflo(qw.x), q1 = bfhi(qw.x), q2 = bflo(qw.y), q3 = bfhi(qw.y);
        const float q4 = bflo(qw.z), q5 = bfhi(qw.z), q6 = bflo(qw.w), q7 = bfhi(qw.w);
        const int s0 = row_start[node], s1 = row_start[node + 1];
        for (int j = s0; j < s1; j += 8) {
            const int jj = j + g;
            const bool valid = jj < s1;
            float p = 0.f;
            if (valid) {
                int s = sorted_src[jj];
                uint4 kw = reinterpret_cast<const uint4*>(k + (size_t)s * D_OUT)[c8];
                p = q0 * bflo(kw.x);
                p = fmaf(q1, bfhi(kw.x), p);
                p = fmaf(q2, bflo(kw.y), p);
                p = fmaf(q3, bfhi(kw.y), p);
                p = fmaf(q4, bflo(kw.z), p);
                p = fmaf(q5, bfhi(kw.z), p);
                p = fmaf(q6, bflo(kw.w), p);
                p = fmaf(q7, bfhi(kw.w), p);
            }
            p += __shfl_xor(p, 1, 8);
            p += __shfl_xor(p, 2, 8);
            p += __shfl_xor(p, 4, 8);
            if (valid && c8 == 0) {
                float a = p * 0.125f;   // 1/sqrt(64)
                alpha_sorted[jj] = a;
                lsum += a;
                lsq += a * a;
            }
        }
    }
#pragma unroll
    for (int off = 1; off < 64; off <<= 1) {
        lsum += __shfl_xor(lsum, off, 64);
        lsq  += __shfl_xor(lsq,  off, 64);
    }
    __shared__ float red[2][4];
    if (lane == 0) { red[0][wid] = lsum; red[1][wid] = lsq; }
    __syncthreads();
    if (t == 0) {
        float* sl = slots + (blockIdx.x & (NSLOT - 1)) * SLOT_STRIDE;
        atomicAdd(&sl[0], red[0][0] + red[0][1] + red[0][2] + red[0][3]);
        atomicAdd(&sl[1], red[1][0] + red[1][1] + red[1][2] + red[1][3]);
    }
}

// ---------------- finalize mean/std (reduce 64 slots) ----------------
__global__ void finalize_stats_kernel(const float* __restrict__ slots,
                                      float* stats, int E) {
    const int lane = threadIdx.x & 63;
    float s  = slots[lane * SLOT_STRIDE];
    float s2 = slots[lane * SLOT_STRIDE + 1];
#pragma unroll
    for (int off = 1; off < 64; off <<= 1) {
        s  += __shfl_xor(s,  off, 64);
        s2 += __shfl_xor(s2, off, 64);
    }
    if (lane == 0) {
        float mean = s / (float)E;
        float var = (s2 - (float)E * mean * mean) / (float)(E - 1);
        stats[2] = mean;
        stats[3] = SCALE_PARAM / sqrtf(var);
    }
}

// ---------------- per-node accumulate: sigmoid + v gather ----------------
__global__ __launch_bounds__(256) void node_gather_kernel(
    const ushortt* __restrict__ v, const int* __restrict__ sorted_src,
    const float* __restrict__ alpha_sorted, const int* __restrict__ row_start,
    const float* __restrict__ stats, float* __restrict__ out, int N)
{
    const int t = threadIdx.x;
    const int wid = t >> 6, lane = t & 63;
    const int g = lane >> 3, c8 = lane & 7;
    const int node = blockIdx.x * 4 + wid;
    if (node >= N) return;
    const float mean = stats[2], coef = stats[3];
    float a0 = 0, a1 = 0, a2 = 0, a3 = 0, a4 = 0, a5 = 0, a6 = 0, a7 = 0;
    const int s0 = row_start[node], s1 = row_start[node + 1];
    for (int j = s0; j < s1; j += 8) {
        const int jj = j + g;
        if (jj < s1) {
            int s = sorted_src[jj];
            float al = alpha_sorted[jj];
            al = (al - mean) * coef;
            al = 1.f / (1.f + __expf(-al));
            uint4 vw = reinterpret_cast<const uint4*>(v + (size_t)s * D_OUT)[c8];
            a0 = fmaf(bflo(vw.x), al, a0); a1 = fmaf(bfhi(vw.x), al, a1);
            a2 = fmaf(bflo(vw.y), al, a2); a3 = fmaf(bfhi(vw.y), al, a3);
            a4 = fmaf(bflo(vw.z), al, a4); a5 = fmaf(bfhi(vw.z), al, a5);
            a6 = fmaf(bflo(vw.w), al, a6); a7 = fmaf(bfhi(vw.w), al, a7);
        }
    }
#pragma unroll
    for (int off = 8; off < 64; off <<= 1) {
        a0 += __shfl_xor(a0, off, 64); a1 += __shfl_xor(a1, off, 64);
        a2 += __shfl_xor(a2, off, 64); a3 += __shfl_xor(a3, off, 64);
        a4 += __shfl_xor(a4, off, 64); a5 += __shfl_xor(a5, off, 64);
        a6 += __shfl_xor(a6, off, 64); a7 += __shfl_xor(a7, off, 64);
    }
    if (g == 0) {
        float* op = out + (size_t)node * D_OUT + c8 * 8;
        float4 c0 = *reinterpret_cast<float4*>(op);
        float4 c1 = *reinterpret_cast<float4*>(op + 4);
        c0.x += a0; c0.y += a1; c0.z += a2; c0.w += a3;
        c1.x += a4; c1.y += a5; c1.z += a6; c1.w += a7;
        *reinterpret_cast<float4*>(op)     = c0;
        *reinterpret_cast<float4*>(op + 4) = c1;
    }
}

extern "C" void kernel_launch(void* const* d_in, const int* in_sizes, int n_in,
                              void* d_out, int out_size, void* d_ws, size_t ws_size,
                              hipStream_t stream) {
    const float* x     = (const float*)d_in[0];
    const int*   eidx  = (const int*)d_in[1];
    const float* Wq    = (const float*)d_in[2];
    const float* bq    = (const float*)d_in[3];
    const float* Wk    = (const float*)d_in[4];
    const float* bk    = (const float*)d_in[5];
    const float* Wv    = (const float*)d_in[6];
    const float* bv    = (const float*)d_in[7];
    const float* Ws    = (const float*)d_in[8];
    const float* bs    = (const float*)d_in[9];
    float* out = (float*)d_out;

    const int N = in_sizes[0] / D_IN;
    const int E = in_sizes[1] / 2;
    const int* src = eidx;
    const int* dst = eidx + E;

    char* base = (char*)d_ws;
    size_t cur = 0;
    auto carve = [&](size_t bytes) -> char* {
        char* p = base + cur;
        cur = (cur + bytes + 255) & ~(size_t)255;
        return p;
    };
    const size_t nodebf = (size_t)N * D_OUT * sizeof(ushortt);
    ushortt* q          = (ushortt*)carve(nodebf);
    ushortt* k          = (ushortt*)carve(nodebf);
    ushortt* v          = (ushortt*)carve(nodebf);
    float* alpha_sorted = (float*)carve((size_t)E * sizeof(float));
    int*   sorted_src   = (int*)carve((size_t)E * sizeof(int));
    // zero region: cnt | slots | stats
    const size_t cnt_b   = ((size_t)N * sizeof(int) + 255) & ~(size_t)255;
    const size_t slots_b = (size_t)NSLOT * SLOT_STRIDE * sizeof(float);
    char*  zreg         = carve(cnt_b + slots_b + 256);
    int*   cnt          = (int*)zreg;
    float* slots        = (float*)(zreg + cnt_b);
    float* stats        = (float*)(zreg + cnt_b + slots_b);
    int*   row_start    = (int*)carve((size_t)(N + 1) * sizeof(int));
    int*   ofs          = (int*)carve((size_t)N * sizeof(int));
    const int NB = (N + 1023) / 1024;
    int*   bsum         = (int*)carve((size_t)NB * sizeof(int));

    hipMemsetAsync(zreg, 0, cnt_b + slots_b + 256, stream);

    // edge-index-only pipeline (independent of GEMM)
    hist_kernel<<<(E / 4 + 255) / 256, 256, 0, stream>>>(dst, cnt, E);
    scan1_kernel<<<NB, 256, 0, stream>>>(cnt, row_start, bsum, N);
    scan2_kernel<<<1, 64, 0, stream>>>(bsum, NB, &row_start[N]);
    scan3_kernel<<<NB, 256, 0, stream>>>(row_start, ofs, bsum, N);
    scatter_sort_kernel<<<(E + 255) / 256, 256, 0, stream>>>(
        src, dst, ofs, sorted_src, E);

    const int gemm_grid = (N + BM - 1) / BM;
    fused_gemm_kernel<<<gemm_grid, 256, 0, stream>>>(
        x, Wq, bq, Wk, bk, Wv, bv, Ws, bs, q, k, v, out, N);

    node_logit_kernel<<<(N + 3) / 4, 256, 0, stream>>>(
        q, k, sorted_src, row_start, alpha_sorted, slots, N);
    finalize_stats_kernel<<<1, 64, 0, stream>>>(slots, stats, E);
    node_gather_kernel<<<(N + 3) / 4, 256, 0, stream>>>(
        v, sorted_src, alpha_sorted, row_start, stats, out, N);
}

// Round 6
// 358.500 us; speedup vs baseline: 2.7698x; 1.1210x over previous
//
#include <hip/hip_runtime.h>
#include <math.h>

#define D_IN 128
#define D_OUT 64
#define BM 64
#define BNT 256
#define KB 32
#define SCALE_PARAM 2.0f
#define NSLOT 64          // spread slots for stats atomics (64B-line spaced)
#define SLOT_STRIDE 16    // floats

typedef unsigned short ushortt;

__device__ __forceinline__ ushortt f2bf(float f) {
    union { float f; unsigned u; } cv; cv.f = f;
    unsigned u = cv.u;
    return (ushortt)((u + 0x7FFFu + ((u >> 16) & 1u)) >> 16);
}
__device__ __forceinline__ float bflo(unsigned w) {
    union { unsigned u; float f; } cv; cv.u = w << 16;
    return cv.f;
}
__device__ __forceinline__ float bfhi(unsigned w) {
    union { unsigned u; float f; } cv; cv.u = w & 0xFFFF0000u;
    return cv.f;
}

// ---------------- fused qkv+skip GEMM ----------------
__global__ __launch_bounds__(256) void fused_gemm_kernel(
    const float* __restrict__ x,
    const float* __restrict__ Wq, const float* __restrict__ bq,
    const float* __restrict__ Wk, const float* __restrict__ bk,
    const float* __restrict__ Wv, const float* __restrict__ bv,
    const float* __restrict__ Ws, const float* __restrict__ bs,
    ushortt* __restrict__ q, ushortt* __restrict__ kk, ushortt* __restrict__ v,
    float* __restrict__ skip, int N)
{
    __shared__ float xs[KB][BM + 4];
    __shared__ float wsh[KB][BNT];

    const int t = threadIdx.x;
    const int row0 = blockIdx.x * BM;
    const int tx = t & 31;
    const int ty = t >> 5;

    float acc[8][8];
#pragma unroll
    for (int i = 0; i < 8; ++i)
#pragma unroll
        for (int j = 0; j < 8; ++j) acc[i][j] = 0.f;

    const int m = t >> 6;
    const int c = t & 63;
    const float* Wm = (m == 0) ? Wq : (m == 1) ? Wk : (m == 2) ? Wv : Ws;

    for (int k0 = 0; k0 < D_IN; k0 += KB) {
#pragma unroll
        for (int r = 0; r < KB; ++r)
            wsh[r][t] = Wm[(k0 + r) * D_OUT + c];
        {
            int r = t >> 2;
            int c4b = t & 3;
#pragma unroll
            for (int it = 0; it < 2; ++it) {
                int cc = c4b + it * 4;
                int grow = row0 + r;
                float4 xv = make_float4(0.f, 0.f, 0.f, 0.f);
                if (grow < N)
                    xv = *reinterpret_cast<const float4*>(&x[(size_t)grow * D_IN + k0 + cc * 4]);
                xs[cc * 4 + 0][r] = xv.x;
                xs[cc * 4 + 1][r] = xv.y;
                xs[cc * 4 + 2][r] = xv.z;
                xs[cc * 4 + 3][r] = xv.w;
            }
        }
        __syncthreads();
#pragma unroll
        for (int kq = 0; kq < KB; ++kq) {
            float a[8], b[8];
            float4 a0 = *reinterpret_cast<const float4*>(&xs[kq][ty * 8]);
            float4 a1 = *reinterpret_cast<const float4*>(&xs[kq][ty * 8 + 4]);
            float4 b0 = *reinterpret_cast<const float4*>(&wsh[kq][tx * 8]);
            float4 b1 = *reinterpret_cast<const float4*>(&wsh[kq][tx * 8 + 4]);
            a[0] = a0.x; a[1] = a0.y; a[2] = a0.z; a[3] = a0.w;
            a[4] = a1.x; a[5] = a1.y; a[6] = a1.z; a[7] = a1.w;
            b[0] = b0.x; b[1] = b0.y; b[2] = b0.z; b[3] = b0.w;
            b[4] = b1.x; b[5] = b1.y; b[6] = b1.z; b[7] = b1.w;
#pragma unroll
            for (int i = 0; i < 8; ++i)
#pragma unroll
                for (int j = 0; j < 8; ++j)
                    acc[i][j] = fmaf(a[i], b[j], acc[i][j]);
        }
        __syncthreads();
    }

    const int mo = (tx * 8) >> 6;
    const int co = (tx * 8) & 63;
    const float* bp = (mo == 0) ? bq : (mo == 1) ? bk : (mo == 2) ? bv : bs;
#pragma unroll
    for (int i = 0; i < 8; ++i) {
        int grow = row0 + ty * 8 + i;
        if (grow >= N) continue;
        float o[8];
#pragma unroll
        for (int j = 0; j < 8; ++j) o[j] = acc[i][j] + bp[co + j];
        if (mo == 3) {
            *reinterpret_cast<float4*>(&skip[(size_t)grow * D_OUT + co])     = make_float4(o[0], o[1], o[2], o[3]);
            *reinterpret_cast<float4*>(&skip[(size_t)grow * D_OUT + co + 4]) = make_float4(o[4], o[5], o[6], o[7]);
        } else {
            ushortt* op = (mo == 0) ? q : (mo == 1) ? kk : v;
            uint4 pk;
            pk.x = (unsigned)f2bf(o[0]) | ((unsigned)f2bf(o[1]) << 16);
            pk.y = (unsigned)f2bf(o[2]) | ((unsigned)f2bf(o[3]) << 16);
            pk.z = (unsigned)f2bf(o[4]) | ((unsigned)f2bf(o[5]) << 16);
            pk.w = (unsigned)f2bf(o[6]) | ((unsigned)f2bf(o[7]) << 16);
            *reinterpret_cast<uint4*>(&op[(size_t)grow * D_OUT + co]) = pk;
        }
    }
}

// ---------------- dst histogram ----------------
__global__ __launch_bounds__(256) void hist_kernel(
    const int* __restrict__ dst, int* __restrict__ cnt, int E)
{
    int base = (blockIdx.x * 256 + threadIdx.x) * 4;
    if (base + 3 < E) {
        int4 d = *reinterpret_cast<const int4*>(&dst[base]);
        atomicAdd(&cnt[d.x], 1); atomicAdd(&cnt[d.y], 1);
        atomicAdd(&cnt[d.z], 1); atomicAdd(&cnt[d.w], 1);
    } else {
        for (int i = base; i < E; ++i) atomicAdd(&cnt[dst[i]], 1);
    }
}

// ---------------- scan phases ----------------
__global__ __launch_bounds__(256) void scan1_kernel(
    const int* __restrict__ cnt, int* __restrict__ row_start,
    int* __restrict__ bsum, int N)
{
    const int t = threadIdx.x;
    const int base = blockIdx.x * 1024 + t * 4;
    int v0 = 0, v1 = 0, v2 = 0, v3 = 0;
    if (base + 3 < N) {
        int4 c = *reinterpret_cast<const int4*>(&cnt[base]);
        v0 = c.x; v1 = c.y; v2 = c.z; v3 = c.w;
    } else {
        if (base < N)     v0 = cnt[base];
        if (base + 1 < N) v1 = cnt[base + 1];
        if (base + 2 < N) v2 = cnt[base + 2];
    }
    const int tsum = v0 + v1 + v2 + v3;
    int x = tsum;
    const int lane = t & 63;
#pragma unroll
    for (int off = 1; off < 64; off <<= 1) {
        int n = __shfl_up(x, off, 64);
        if (lane >= off) x += n;
    }
    __shared__ int wsum[4];
    const int wid = t >> 6;
    if (lane == 63) wsum[wid] = x;
    __syncthreads();
    int wofs = 0;
    for (int w = 0; w < wid; ++w) wofs += wsum[w];
    const int incl = x + wofs;
    const int excl = incl - tsum;
    if (base < N)     row_start[base]     = excl;
    if (base + 1 < N) row_start[base + 1] = excl + v0;
    if (base + 2 < N) row_start[base + 2] = excl + v0 + v1;
    if (base + 3 < N) row_start[base + 3] = excl + v0 + v1 + v2;
    if (t == 255) bsum[blockIdx.x] = incl;
}

__global__ void scan2_kernel(int* bsum, int NB, int* row_start_N) {
    if (threadIdx.x == 0) {
        int run = 0;
        for (int i = 0; i < NB; ++i) {
            int tv = bsum[i];
            bsum[i] = run;
            run += tv;
        }
        *row_start_N = run;
    }
}

__global__ __launch_bounds__(256) void scan3_kernel(
    int* __restrict__ row_start, int* __restrict__ ofs,
    const int* __restrict__ bsum, int N)
{
    const int base = blockIdx.x * 1024 + threadIdx.x * 4;
    const int add = bsum[blockIdx.x];
#pragma unroll
    for (int i = 0; i < 4; ++i) {
        if (base + i < N) {
            int vv = row_start[base + i] + add;
            row_start[base + i] = vv;
            ofs[base + i] = vv;
        }
    }
}

// ---------------- XCD-partitioned bucket scatter ----------------
// Node range p = blockIdx&7 (== XCD id under round-robin dispatch) so each
// sorted_src region is written by one XCD's L2 only -> full lines, no
// cross-XCD partial-line writeback thrash.
__global__ __launch_bounds__(256) void scatter_sort_kernel(
    const int* __restrict__ src, const int* __restrict__ dst,
    int* __restrict__ ofs, int* __restrict__ sorted_src, int E, int N)
{
    const int part = blockIdx.x & 7;
    const int gb   = blockIdx.x >> 3;
    const int nblk = gridDim.x >> 3;
    const int lo = (int)(((long long)part * N) >> 3);
    const int hi = (int)(((long long)(part + 1) * N) >> 3);
    const int stride = nblk * 256 * 4;

    for (int base = (gb * 256 + threadIdx.x) * 4; base < E; base += stride) {
        if (base + 3 < E) {
            int4 d4 = *reinterpret_cast<const int4*>(&dst[base]);
            int4 s4 = *reinterpret_cast<const int4*>(&src[base]);
            if (d4.x >= lo && d4.x < hi) sorted_src[atomicAdd(&ofs[d4.x], 1)] = s4.x;
            if (d4.y >= lo && d4.y < hi) sorted_src[atomicAdd(&ofs[d4.y], 1)] = s4.y;
            if (d4.z >= lo && d4.z < hi) sorted_src[atomicAdd(&ofs[d4.z], 1)] = s4.z;
            if (d4.w >= lo && d4.w < hi) sorted_src[atomicAdd(&ofs[d4.w], 1)] = s4.w;
        } else {
            for (int i = base; i < E; ++i) {
                int d = dst[i];
                if (d >= lo && d < hi) sorted_src[atomicAdd(&ofs[d], 1)] = src[i];
            }
        }
    }
}

// ---------------- per-node logits + stats (spread-slot atomics) --------
__global__ __launch_bounds__(256) void node_logit_kernel(
    const ushortt* __restrict__ q, const ushortt* __restrict__ k,
    const int* __restrict__ sorted_src, const int* __restrict__ row_start,
    float* __restrict__ alpha_sorted, float* __restrict__ slots, int N)
{
    const int t = threadIdx.x;
    const int wid = t >> 6, lane = t & 63;
    const int g = lane >> 3;       // edge slot 0..7
    const int c8 = lane & 7;       // channel octet
    const int node = blockIdx.x * 4 + wid;
    float lsum = 0.f, lsq = 0.f;
    if (node < N) {
        uint4 qw = reinterpret_cast<const uint4*>(q + (size_t)node * D_OUT)[c8];
        const float q0 = bflo(qw.x), q1 = bfhi(qw.x), q2 = bflo(qw.y), q3 = bfhi(qw.y);
        const float q4 = bflo(qw.z), q5 = bfhi(qw.z), q6 = bflo(qw.w), q7 = bfhi(qw.w);
        const int s0 = row_start[node], s1 = row_start[node + 1];
        for (int j = s0; j < s1; j += 8) {
            const int jj = j + g;
            const bool valid = jj < s1;
            float p = 0.f;
            if (valid) {
                int s = sorted_src[jj];
                uint4 kw = reinterpret_cast<const uint4*>(k + (size_t)s * D_OUT)[c8];
                p = q0 * bflo(kw.x);
                p = fmaf(q1, bfhi(kw.x), p);
                p = fmaf(q2, bflo(kw.y), p);
                p = fmaf(q3, bfhi(kw.y), p);
                p = fmaf(q4, bflo(kw.z), p);
                p = fmaf(q5, bfhi(kw.z), p);
                p = fmaf(q6, bflo(kw.w), p);
                p = fmaf(q7, bfhi(kw.w), p);
            }
            p += __shfl_xor(p, 1, 8);
            p += __shfl_xor(p, 2, 8);
            p += __shfl_xor(p, 4, 8);
            if (valid && c8 == 0) {
                float a = p * 0.125f;   // 1/sqrt(64)
                alpha_sorted[jj] = a;
                lsum += a;
                lsq += a * a;
            }
        }
    }
#pragma unroll
    for (int off = 1; off < 64; off <<= 1) {
        lsum += __shfl_xor(lsum, off, 64);
        lsq  += __shfl_xor(lsq,  off, 64);
    }
    __shared__ float red[2][4];
    if (lane == 0) { red[0][wid] = lsum; red[1][wid] = lsq; }
    __syncthreads();
    if (t == 0) {
        float* sl = slots + (blockIdx.x & (NSLOT - 1)) * SLOT_STRIDE;
        atomicAdd(&sl[0], red[0][0] + red[0][1] + red[0][2] + red[0][3]);
        atomicAdd(&sl[1], red[1][0] + red[1][1] + red[1][2] + red[1][3]);
    }
}

// ---------------- finalize mean/std (reduce 64 slots) ----------------
__global__ void finalize_stats_kernel(const float* __restrict__ slots,
                                      float* stats, int E) {
    const int lane = threadIdx.x & 63;
    float s  = slots[lane * SLOT_STRIDE];
    float s2 = slots[lane * SLOT_STRIDE + 1];
#pragma unroll
    for (int off = 1; off < 64; off <<= 1) {
        s  += __shfl_xor(s,  off, 64);
        s2 += __shfl_xor(s2, off, 64);
    }
    if (lane == 0) {
        float mean = s / (float)E;
        float var = (s2 - (float)E * mean * mean) / (float)(E - 1);
        stats[2] = mean;
        stats[3] = SCALE_PARAM / sqrtf(var);
    }
}

// ---------------- per-node accumulate: sigmoid + v gather ----------------
__global__ __launch_bounds__(256) void node_gather_kernel(
    const ushortt* __restrict__ v, const int* __restrict__ sorted_src,
    const float* __restrict__ alpha_sorted, const int* __restrict__ row_start,
    const float* __restrict__ stats, float* __restrict__ out, int N)
{
    const int t = threadIdx.x;
    const int wid = t >> 6, lane = t & 63;
    const int g = lane >> 3, c8 = lane & 7;
    const int node = blockIdx.x * 4 + wid;
    if (node >= N) return;
    const float mean = stats[2], coef = stats[3];
    float a0 = 0, a1 = 0, a2 = 0, a3 = 0, a4 = 0, a5 = 0, a6 = 0, a7 = 0;
    const int s0 = row_start[node], s1 = row_start[node + 1];
    for (int j = s0; j < s1; j += 8) {
        const int jj = j + g;
        if (jj < s1) {
            int s = sorted_src[jj];
            float al = alpha_sorted[jj];
            al = (al - mean) * coef;
            al = 1.f / (1.f + __expf(-al));
            uint4 vw = reinterpret_cast<const uint4*>(v + (size_t)s * D_OUT)[c8];
            a0 = fmaf(bflo(vw.x), al, a0); a1 = fmaf(bfhi(vw.x), al, a1);
            a2 = fmaf(bflo(vw.y), al, a2); a3 = fmaf(bfhi(vw.y), al, a3);
            a4 = fmaf(bflo(vw.z), al, a4); a5 = fmaf(bfhi(vw.z), al, a5);
            a6 = fmaf(bflo(vw.w), al, a6); a7 = fmaf(bfhi(vw.w), al, a7);
        }
    }
#pragma unroll
    for (int off = 8; off < 64; off <<= 1) {
        a0 += __shfl_xor(a0, off, 64); a1 += __shfl_xor(a1, off, 64);
        a2 += __shfl_xor(a2, off, 64); a3 += __shfl_xor(a3, off, 64);
        a4 += __shfl_xor(a4, off, 64); a5 += __shfl_xor(a5, off, 64);
        a6 += __shfl_xor(a6, off, 64); a7 += __shfl_xor(a7, off, 64);
    }
    if (g == 0) {
        float* op = out + (size_t)node * D_OUT + c8 * 8;
        float4 c0 = *reinterpret_cast<float4*>(op);
        float4 c1 = *reinterpret_cast<float4*>(op + 4);
        c0.x += a0; c0.y += a1; c0.z += a2; c0.w += a3;
        c1.x += a4; c1.y += a5; c1.z += a6; c1.w += a7;
        *reinterpret_cast<float4*>(op)     = c0;
        *reinterpret_cast<float4*>(op + 4) = c1;
    }
}

extern "C" void kernel_launch(void* const* d_in, const int* in_sizes, int n_in,
                              void* d_out, int out_size, void* d_ws, size_t ws_size,
                              hipStream_t stream) {
    const float* x     = (const float*)d_in[0];
    const int*   eidx  = (const int*)d_in[1];
    const float* Wq    = (const float*)d_in[2];
    const float* bq    = (const float*)d_in[3];
    const float* Wk    = (const float*)d_in[4];
    const float* bk    = (const float*)d_in[5];
    const float* Wv    = (const float*)d_in[6];
    const float* bv    = (const float*)d_in[7];
    const float* Ws    = (const float*)d_in[8];
    const float* bs    = (const float*)d_in[9];
    float* out = (float*)d_out;

    const int N = in_sizes[0] / D_IN;
    const int E = in_sizes[1] / 2;
    const int* src = eidx;
    const int* dst = eidx + E;

    char* base = (char*)d_ws;
    size_t cur = 0;
    auto carve = [&](size_t bytes) -> char* {
        char* p = base + cur;
        cur = (cur + bytes + 255) & ~(size_t)255;
        return p;
    };
    const size_t nodebf = (size_t)N * D_OUT * sizeof(ushortt);
    ushortt* q          = (ushortt*)carve(nodebf);
    ushortt* k          = (ushortt*)carve(nodebf);
    ushortt* v          = (ushortt*)carve(nodebf);
    float* alpha_sorted = (float*)carve((size_t)E * sizeof(float));
    int*   sorted_src   = (int*)carve((size_t)E * sizeof(int));
    // zero region: cnt | slots | stats
    const size_t cnt_b   = ((size_t)N * sizeof(int) + 255) & ~(size_t)255;
    const size_t slots_b = (size_t)NSLOT * SLOT_STRIDE * sizeof(float);
    char*  zreg         = carve(cnt_b + slots_b + 256);
    int*   cnt          = (int*)zreg;
    float* slots        = (float*)(zreg + cnt_b);
    float* stats        = (float*)(zreg + cnt_b + slots_b);
    int*   row_start    = (int*)carve((size_t)(N + 1) * sizeof(int));
    int*   ofs          = (int*)carve((size_t)N * sizeof(int));
    const int NB = (N + 1023) / 1024;
    int*   bsum         = (int*)carve((size_t)NB * sizeof(int));

    hipMemsetAsync(zreg, 0, cnt_b + slots_b + 256, stream);

    // edge-index-only pipeline (independent of GEMM)
    hist_kernel<<<(E / 4 + 255) / 256, 256, 0, stream>>>(dst, cnt, E);
    scan1_kernel<<<NB, 256, 0, stream>>>(cnt, row_start, bsum, N);
    scan2_kernel<<<1, 64, 0, stream>>>(bsum, NB, &row_start[N]);
    scan3_kernel<<<NB, 256, 0, stream>>>(row_start, ofs, bsum, N);
    scatter_sort_kernel<<<2048, 256, 0, stream>>>(
        src, dst, ofs, sorted_src, E, N);

    const int gemm_grid = (N + BM - 1) / BM;
    fused_gemm_kernel<<<gemm_grid, 256, 0, stream>>>(
        x, Wq, bq, Wk, bk, Wv, bv, Ws, bs, q, k, v, out, N);

    node_logit_kernel<<<(N + 3) / 4, 256, 0, stream>>>(
        q, k, sorted_src, row_start, alpha_sorted, slots, N);
    finalize_stats_kernel<<<1, 64, 0, stream>>>(slots, stats, E);
    node_gather_kernel<<<(N + 3) / 4, 256, 0, stream>>>(
        v, sorted_src, alpha_sorted, row_start, stats, out, N);
}

// Round 7
// 302.988 us; speedup vs baseline: 3.2773x; 1.1832x over previous
//
#include <hip/hip_runtime.h>
#include <math.h>

#define D_IN 128
#define D_OUT 64
#define SCALE_PARAM 2.0f
#define NSLOT 64          // spread slots for stats atomics (64B-line spaced)
#define SLOT_STRIDE 16    // floats

typedef unsigned short ushortt;
typedef __attribute__((ext_vector_type(8))) short bf16x8;
typedef __attribute__((ext_vector_type(4))) float f32x4;

__device__ __forceinline__ ushortt f2bf(float f) {
    union { float f; unsigned u; } cv; cv.f = f;
    unsigned u = cv.u;
    return (ushortt)((u + 0x7FFFu + ((u >> 16) & 1u)) >> 16);
}
__device__ __forceinline__ float bflo(unsigned w) {
    union { unsigned u; float f; } cv; cv.u = w << 16;
    return cv.f;
}
__device__ __forceinline__ float bfhi(unsigned w) {
    union { unsigned u; float f; } cv; cv.u = w & 0xFFFF0000u;
    return cv.f;
}

// ---------------- MFMA fused qkv+skip GEMM ----------------
// 64 rows/block, 4 waves; wave w computes matrix w (0=q,1=k,2=v,3=skip).
// A (x tile) staged bf16 in LDS with XOR swizzle; B (W) frags from L2.
__global__ __launch_bounds__(256) void fused_gemm_kernel(
    const float* __restrict__ x,
    const float* __restrict__ Wq, const float* __restrict__ bq,
    const float* __restrict__ Wk, const float* __restrict__ bk,
    const float* __restrict__ Wv, const float* __restrict__ bv,
    const float* __restrict__ Ws, const float* __restrict__ bs,
    ushortt* __restrict__ q, ushortt* __restrict__ kk, ushortt* __restrict__ v,
    float* __restrict__ skip, int N)
{
    __shared__ __align__(16) ushortt As[64 * 128];   // 16 KB, swizzled
    char* AsB = (char*)As;

    const int t = threadIdx.x;
    const int w = t >> 6;          // wave id = matrix id
    const int l = t & 63;
    const int cl = l & 15;         // col-in-frag / row-in-frag lane part
    const int kb8 = (l >> 4) * 8;  // k-element base for A/B frags
    const int row0 = blockIdx.x * 64;

    const float* Wm = (w == 0) ? Wq : (w == 1) ? Wk : (w == 2) ? Wv : Ws;
    const float* bp = (w == 0) ? bq : (w == 1) ? bk : (w == 2) ? bv : bs;

    // ---- B fragments: bfr[ks][ci], elem b -> Wm[ks*32+kb8+b][ci*16+cl]
    union U8 { uint4 u; bf16x8 v; };
    bf16x8 bfr[4][4];
#pragma unroll
    for (int ks = 0; ks < 4; ++ks)
#pragma unroll
        for (int ci = 0; ci < 4; ++ci) {
            unsigned pk[4];
#pragma unroll
            for (int p = 0; p < 4; ++p) {
                float f0 = Wm[(ks * 32 + kb8 + 2 * p)     * D_OUT + ci * 16 + cl];
                float f1 = Wm[(ks * 32 + kb8 + 2 * p + 1) * D_OUT + ci * 16 + cl];
                pk[p] = (unsigned)f2bf(f0) | ((unsigned)f2bf(f1) << 16);
            }
            U8 tmp; tmp.u = make_uint4(pk[0], pk[1], pk[2], pk[3]);
            bfr[ks][ci] = tmp.v;
        }
    float bias_r[4];
#pragma unroll
    for (int ci = 0; ci < 4; ++ci) bias_r[ci] = bp[ci * 16 + cl];

    // ---- stage x tile (64 rows x 128) -> bf16 LDS, swizzled
#pragma unroll
    for (int i = 0; i < 8; ++i) {
        int f = i * 256 + t;           // float4 slot (2048 per tile)
        int r = f >> 5;                // 32 float4 per row
        int k4 = f & 31;
        int grow = row0 + r;
        float4 xv = make_float4(0.f, 0.f, 0.f, 0.f);
        if (grow < N)
            xv = *reinterpret_cast<const float4*>(&x[(size_t)grow * D_IN + k4 * 4]);
        uint2 pk;
        pk.x = (unsigned)f2bf(xv.x) | ((unsigned)f2bf(xv.y) << 16);
        pk.y = (unsigned)f2bf(xv.z) | ((unsigned)f2bf(xv.w) << 16);
        int addr = r * 256 + ((k4 * 8) ^ ((r & 7) << 4));
        *reinterpret_cast<uint2*>(AsB + addr) = pk;
    }
    __syncthreads();

    // ---- MFMA: acc[ri][ci] over 4 K-steps
    f32x4 acc[4][4];
#pragma unroll
    for (int ri = 0; ri < 4; ++ri)
#pragma unroll
        for (int ci = 0; ci < 4; ++ci) acc[ri][ci] = (f32x4)(0.f);

#pragma unroll
    for (int ks = 0; ks < 4; ++ks) {
        bf16x8 afr[4];
#pragma unroll
        for (int ri = 0; ri < 4; ++ri) {
            int row = ri * 16 + cl;
            int kby = ks * 64 + kb8 * 2;
            int addr = row * 256 + (kby ^ ((row & 7) << 4));
            afr[ri] = *reinterpret_cast<const bf16x8*>(AsB + addr);
        }
#pragma unroll
        for (int ri = 0; ri < 4; ++ri)
#pragma unroll
            for (int ci = 0; ci < 4; ++ci)
                acc[ri][ci] = __builtin_amdgcn_mfma_f32_16x16x32_bf16(
                    afr[ri], bfr[ks][ci], acc[ri][ci], 0, 0, 0);
    }

    // ---- epilogue: C/D map col=lane&15, row=(lane>>4)*4+reg
    const int rbase = (l >> 4) * 4;
    ushortt* qkv = (w == 0) ? q : (w == 1) ? kk : v;
#pragma unroll
    for (int ri = 0; ri < 4; ++ri)
#pragma unroll
        for (int reg = 0; reg < 4; ++reg) {
            int grow = row0 + ri * 16 + rbase + reg;
            if (grow >= N) continue;
#pragma unroll
            for (int ci = 0; ci < 4; ++ci) {
                float val = acc[ri][ci][reg] + bias_r[ci];
                int col = ci * 16 + cl;
                if (w == 3) skip[(size_t)grow * D_OUT + col] = val;
                else        qkv[(size_t)grow * D_OUT + col] = f2bf(val);
            }
        }
}

// ---------------- dst histogram ----------------
__global__ __launch_bounds__(256) void hist_kernel(
    const int* __restrict__ dst, int* __restrict__ cnt, int E)
{
    int base = (blockIdx.x * 256 + threadIdx.x) * 4;
    if (base + 3 < E) {
        int4 d = *reinterpret_cast<const int4*>(&dst[base]);
        atomicAdd(&cnt[d.x], 1); atomicAdd(&cnt[d.y], 1);
        atomicAdd(&cnt[d.z], 1); atomicAdd(&cnt[d.w], 1);
    } else {
        for (int i = base; i < E; ++i) atomicAdd(&cnt[dst[i]], 1);
    }
}

// ---------------- scan phases ----------------
__global__ __launch_bounds__(256) void scan1_kernel(
    const int* __restrict__ cnt, int* __restrict__ row_start,
    int* __restrict__ bsum, int N)
{
    const int t = threadIdx.x;
    const int base = blockIdx.x * 1024 + t * 4;
    int v0 = 0, v1 = 0, v2 = 0, v3 = 0;
    if (base + 3 < N) {
        int4 c = *reinterpret_cast<const int4*>(&cnt[base]);
        v0 = c.x; v1 = c.y; v2 = c.z; v3 = c.w;
    } else {
        if (base < N)     v0 = cnt[base];
        if (base + 1 < N) v1 = cnt[base + 1];
        if (base + 2 < N) v2 = cnt[base + 2];
    }
    const int tsum = v0 + v1 + v2 + v3;
    int x = tsum;
    const int lane = t & 63;
#pragma unroll
    for (int off = 1; off < 64; off <<= 1) {
        int n = __shfl_up(x, off, 64);
        if (lane >= off) x += n;
    }
    __shared__ int wsum[4];
    const int wid = t >> 6;
    if (lane == 63) wsum[wid] = x;
    __syncthreads();
    int wofs = 0;
    for (int w = 0; w < wid; ++w) wofs += wsum[w];
    const int incl = x + wofs;
    const int excl = incl - tsum;
    if (base < N)     row_start[base]     = excl;
    if (base + 1 < N) row_start[base + 1] = excl + v0;
    if (base + 2 < N) row_start[base + 2] = excl + v0 + v1;
    if (base + 3 < N) row_start[base + 3] = excl + v0 + v1 + v2;
    if (t == 255) bsum[blockIdx.x] = incl;
}

__global__ void scan2_kernel(int* bsum, int NB, int* row_start_N) {
    if (threadIdx.x == 0) {
        int run = 0;
        for (int i = 0; i < NB; ++i) {
            int tv = bsum[i];
            bsum[i] = run;
            run += tv;
        }
        *row_start_N = run;
    }
}

__global__ __launch_bounds__(256) void scan3_kernel(
    int* __restrict__ row_start, int* __restrict__ ofs,
    const int* __restrict__ bsum, int N)
{
    const int base = blockIdx.x * 1024 + threadIdx.x * 4;
    const int add = bsum[blockIdx.x];
#pragma unroll
    for (int i = 0; i < 4; ++i) {
        if (base + i < N) {
            int vv = row_start[base + i] + add;
            row_start[base + i] = vv;
            ofs[base + i] = vv;
        }
    }
}

// ---------------- XCD-partitioned bucket scatter ----------------
__global__ __launch_bounds__(256) void scatter_sort_kernel(
    const int* __restrict__ src, const int* __restrict__ dst,
    int* __restrict__ ofs, int* __restrict__ sorted_src, int E, int N)
{
    const int part = blockIdx.x & 7;
    const int gb   = blockIdx.x >> 3;
    const int nblk = gridDim.x >> 3;
    const int lo = (int)(((long long)part * N) >> 3);
    const int hi = (int)(((long long)(part + 1) * N) >> 3);
    const int stride = nblk * 256 * 4;

    for (int base = (gb * 256 + threadIdx.x) * 4; base < E; base += stride) {
        if (base + 3 < E) {
            int4 d4 = *reinterpret_cast<const int4*>(&dst[base]);
            int4 s4 = *reinterpret_cast<const int4*>(&src[base]);
            if (d4.x >= lo && d4.x < hi) sorted_src[atomicAdd(&ofs[d4.x], 1)] = s4.x;
            if (d4.y >= lo && d4.y < hi) sorted_src[atomicAdd(&ofs[d4.y], 1)] = s4.y;
            if (d4.z >= lo && d4.z < hi) sorted_src[atomicAdd(&ofs[d4.z], 1)] = s4.z;
            if (d4.w >= lo && d4.w < hi) sorted_src[atomicAdd(&ofs[d4.w], 1)] = s4.w;
        } else {
            for (int i = base; i < E; ++i) {
                int d = dst[i];
                if (d >= lo && d < hi) sorted_src[atomicAdd(&ofs[d], 1)] = src[i];
            }
        }
    }
}

// ---------------- per-node logits + stats (spread-slot atomics) --------
__global__ __launch_bounds__(256) void node_logit_kernel(
    const ushortt* __restrict__ q, const ushortt* __restrict__ k,
    const int* __restrict__ sorted_src, const int* __restrict__ row_start,
    float* __restrict__ alpha_sorted, float* __restrict__ slots, int N)
{
    const int t = threadIdx.x;
    const int wid = t >> 6, lane = t & 63;
    const int g = lane >> 3;       // edge slot 0..7
    const int c8 = lane & 7;       // channel octet
    const int node = blockIdx.x * 4 + wid;
    float lsum = 0.f, lsq = 0.f;
    if (node < N) {
        uint4 qw = reinterpret_cast<const uint4*>(q + (size_t)node * D_OUT)[c8];
        const float q0 = bflo(qw.x), q1 = bfhi(qw.x), q2 = bflo(qw.y), q3 = bfhi(qw.y);
        const float q4 = bflo(qw.z), q5 = bfhi(qw.z), q6 = bflo(qw.w), q7 = bfhi(qw.w);
        const int s0 = row_start[node], s1 = row_start[node + 1];
        for (int j = s0; j < s1; j += 8) {
            const int jj = j + g;
            const bool valid = jj < s1;
            float p = 0.f;
            if (valid) {
                int s = sorted_src[jj];
                uint4 kw = reinterpret_cast<const uint4*>(k + (size_t)s * D_OUT)[c8];
                p = q0 * bflo(kw.x);
                p = fmaf(q1, bfhi(kw.x), p);
                p = fmaf(q2, bflo(kw.y), p);
                p = fmaf(q3, bfhi(kw.y), p);
                p = fmaf(q4, bflo(kw.z), p);
                p = fmaf(q5, bfhi(kw.z), p);
                p = fmaf(q6, bflo(kw.w), p);
                p = fmaf(q7, bfhi(kw.w), p);
            }
            p += __shfl_xor(p, 1, 8);
            p += __shfl_xor(p, 2, 8);
            p += __shfl_xor(p, 4, 8);
            if (valid && c8 == 0) {
                float a = p * 0.125f;   // 1/sqrt(64)
                alpha_sorted[jj] = a;
                lsum += a;
                lsq += a * a;
            }
        }
    }
#pragma unroll
    for (int off = 1; off < 64; off <<= 1) {
        lsum += __shfl_xor(lsum, off, 64);
        lsq  += __shfl_xor(lsq,  off, 64);
    }
    __shared__ float red[2][4];
    if (lane == 0) { red[0][wid] = lsum; red[1][wid] = lsq; }
    __syncthreads();
    if (t == 0) {
        float* sl = slots + (blockIdx.x & (NSLOT - 1)) * SLOT_STRIDE;
        atomicAdd(&sl[0], red[0][0] + red[0][1] + red[0][2] + red[0][3]);
        atomicAdd(&sl[1], red[1][0] + red[1][1] + red[1][2] + red[1][3]);
    }
}

// ---------------- finalize mean/std (reduce 64 slots) ----------------
__global__ void finalize_stats_kernel(const float* __restrict__ slots,
                                      float* stats, int E) {
    const int lane = threadIdx.x & 63;
    float s  = slots[lane * SLOT_STRIDE];
    float s2 = slots[lane * SLOT_STRIDE + 1];
#pragma unroll
    for (int off = 1; off < 64; off <<= 1) {
        s  += __shfl_xor(s,  off, 64);
        s2 += __shfl_xor(s2, off, 64);
    }
    if (lane == 0) {
        float mean = s / (float)E;
        float var = (s2 - (float)E * mean * mean) / (float)(E - 1);
        stats[2] = mean;
        stats[3] = SCALE_PARAM / sqrtf(var);
    }
}

// ---------------- per-node accumulate: sigmoid + v gather ----------------
__global__ __launch_bounds__(256) void node_gather_kernel(
    const ushortt* __restrict__ v, const int* __restrict__ sorted_src,
    const float* __restrict__ alpha_sorted, const int* __restrict__ row_start,
    const float* __restrict__ stats, float* __restrict__ out, int N)
{
    const int t = threadIdx.x;
    const int wid = t >> 6, lane = t & 63;
    const int g = lane >> 3, c8 = lane & 7;
    const int node = blockIdx.x * 4 + wid;
    if (node >= N) return;
    const float mean = stats[2], coef = stats[3];
    float a0 = 0, a1 = 0, a2 = 0, a3 = 0, a4 = 0, a5 = 0, a6 = 0, a7 = 0;
    const int s0 = row_start[node], s1 = row_start[node + 1];
    for (int j = s0; j < s1; j += 8) {
        const int jj = j + g;
        if (jj < s1) {
            int s = sorted_src[jj];
            float al = alpha_sorted[jj];
            al = (al - mean) * coef;
            al = 1.f / (1.f + __expf(-al));
            uint4 vw = reinterpret_cast<const uint4*>(v + (size_t)s * D_OUT)[c8];
            a0 = fmaf(bflo(vw.x), al, a0); a1 = fmaf(bfhi(vw.x), al, a1);
            a2 = fmaf(bflo(vw.y), al, a2); a3 = fmaf(bfhi(vw.y), al, a3);
            a4 = fmaf(bflo(vw.z), al, a4); a5 = fmaf(bfhi(vw.z), al, a5);
            a6 = fmaf(bflo(vw.w), al, a6); a7 = fmaf(bfhi(vw.w), al, a7);
        }
    }
#pragma unroll
    for (int off = 8; off < 64; off <<= 1) {
        a0 += __shfl_xor(a0, off, 64); a1 += __shfl_xor(a1, off, 64);
        a2 += __shfl_xor(a2, off, 64); a3 += __shfl_xor(a3, off, 64);
        a4 += __shfl_xor(a4, off, 64); a5 += __shfl_xor(a5, off, 64);
        a6 += __shfl_xor(a6, off, 64); a7 += __shfl_xor(a7, off, 64);
    }
    if (g == 0) {
        float* op = out + (size_t)node * D_OUT + c8 * 8;
        float4 c0 = *reinterpret_cast<float4*>(op);
        float4 c1 = *reinterpret_cast<float4*>(op + 4);
        c0.x += a0; c0.y += a1; c0.z += a2; c0.w += a3;
        c1.x += a4; c1.y += a5; c1.z += a6; c1.w += a7;
        *reinterpret_cast<float4*>(op)     = c0;
        *reinterpret_cast<float4*>(op + 4) = c1;
    }
}

extern "C" void kernel_launch(void* const* d_in, const int* in_sizes, int n_in,
                              void* d_out, int out_size, void* d_ws, size_t ws_size,
                              hipStream_t stream) {
    const float* x     = (const float*)d_in[0];
    const int*   eidx  = (const int*)d_in[1];
    const float* Wq    = (const float*)d_in[2];
    const float* bq    = (const float*)d_in[3];
    const float* Wk    = (const float*)d_in[4];
    const float* bk    = (const float*)d_in[5];
    const float* Wv    = (const float*)d_in[6];
    const float* bv    = (const float*)d_in[7];
    const float* Ws    = (const float*)d_in[8];
    const float* bs    = (const float*)d_in[9];
    float* out = (float*)d_out;

    const int N = in_sizes[0] / D_IN;
    const int E = in_sizes[1] / 2;
    const int* src = eidx;
    const int* dst = eidx + E;

    char* base = (char*)d_ws;
    size_t cur = 0;
    auto carve = [&](size_t bytes) -> char* {
        char* p = base + cur;
        cur = (cur + bytes + 255) & ~(size_t)255;
        return p;
    };
    const size_t nodebf = (size_t)N * D_OUT * sizeof(ushortt);
    ushortt* q          = (ushortt*)carve(nodebf);
    ushortt* k          = (ushortt*)carve(nodebf);
    ushortt* v          = (ushortt*)carve(nodebf);
    float* alpha_sorted = (float*)carve((size_t)E * sizeof(float));
    int*   sorted_src   = (int*)carve((size_t)E * sizeof(int));
    // zero region: cnt | slots | stats
    const size_t cnt_b   = ((size_t)N * sizeof(int) + 255) & ~(size_t)255;
    const size_t slots_b = (size_t)NSLOT * SLOT_STRIDE * sizeof(float);
    char*  zreg         = carve(cnt_b + slots_b + 256);
    int*   cnt          = (int*)zreg;
    float* slots        = (float*)(zreg + cnt_b);
    float* stats        = (float*)(zreg + cnt_b + slots_b);
    int*   row_start    = (int*)carve((size_t)(N + 1) * sizeof(int));
    int*   ofs          = (int*)carve((size_t)N * sizeof(int));
    const int NB = (N + 1023) / 1024;
    int*   bsum         = (int*)carve((size_t)NB * sizeof(int));

    hipMemsetAsync(zreg, 0, cnt_b + slots_b + 256, stream);

    // edge-index-only pipeline (independent of GEMM)
    hist_kernel<<<(E / 4 + 255) / 256, 256, 0, stream>>>(dst, cnt, E);
    scan1_kernel<<<NB, 256, 0, stream>>>(cnt, row_start, bsum, N);
    scan2_kernel<<<1, 64, 0, stream>>>(bsum, NB, &row_start[N]);
    scan3_kernel<<<NB, 256, 0, stream>>>(row_start, ofs, bsum, N);
    scatter_sort_kernel<<<2048, 256, 0, stream>>>(
        src, dst, ofs, sorted_src, E, N);

    const int gemm_grid = (N + 63) / 64;
    fused_gemm_kernel<<<gemm_grid, 256, 0, stream>>>(
        x, Wq, bq, Wk, bk, Wv, bv, Ws, bs, q, k, v, out, N);

    node_logit_kernel<<<(N + 3) / 4, 256, 0, stream>>>(
        q, k, sorted_src, row_start, alpha_sorted, slots, N);
    finalize_stats_kernel<<<1, 64, 0, stream>>>(slots, stats, E);
    node_gather_kernel<<<(N + 3) / 4, 256, 0, stream>>>(
        v, sorted_src, alpha_sorted, row_start, stats, out, N);
}